// Round 2
// baseline (4763.596 us; speedup 1.0000x reference)
//
#include <hip/hip_runtime.h>
#include <hip/hip_bf16.h>

#define VOCAB 5000
#define HIDDEN 1024
#define SEQ 128
#define BATCH 64

typedef __hip_bfloat16 bf16;
typedef short bf16x8 __attribute__((ext_vector_type(8)));   // 8 bf16 = 4 VGPRs (MFMA A/B frag)
typedef float f32x4 __attribute__((ext_vector_type(4)));    // MFMA C/D frag

__device__ __forceinline__ float b2f(bf16 v) { return __bfloat162float(v); }

// ---------------------------------------------------------------------------
// Dtype self-detection: inspect first 64 words (128 halves) of W_ih1.
// bf16 data: every half is a weight with |w| <= 0.03125 -> bf16 exp <= 122.
// fp32 data: low halves are random mantissa bits -> ~50% have exp >= 127.
// Uniform across lanes/blocks; data is identical every call (graph-safe).
// ---------------------------------------------------------------------------
__device__ __forceinline__ bool detect_fp32(const void* w) {
    const unsigned* p = (const unsigned*)w;
    unsigned big = 0;
    #pragma unroll
    for (int i = 0; i < 64; ++i) {
        unsigned e = (p[i] >> 7) & 0xFFu;   // exp field of the LOW bf16 half
        big |= (e >= 127u) ? 1u : 0u;
    }
    return big != 0;
}

// Normalize a weight matrix (fp32 or bf16 source) into a bf16 ws copy.
__global__ __launch_bounds__(256) void convert_w(const void* __restrict__ src,
                                                 bf16* __restrict__ dst, int n,
                                                 const void* __restrict__ det) {
    const bool f32 = detect_fp32(det);
    int i = (blockIdx.x * 256 + threadIdx.x) * 4;
    if (f32) {
        const float* s = (const float*)src;
        #pragma unroll
        for (int j = 0; j < 4; ++j) if (i + j < n) dst[i + j] = __float2bfloat16(s[i + j]);
    } else {
        const bf16* s = (const bf16*)src;
        #pragma unroll
        for (int j = 0; j < 4; ++j) if (i + j < n) dst[i + j] = s[i + j];
    }
}

// dst[i] = a[i] (+ b[i]) as fp32, from either source dtype.
__global__ __launch_bounds__(256) void make_bias(const void* __restrict__ a,
                                                 const void* __restrict__ b,
                                                 float* __restrict__ dst, int n,
                                                 const void* __restrict__ det) {
    const bool f32 = detect_fp32(det);
    int i = blockIdx.x * 256 + threadIdx.x;
    if (i >= n) return;
    float v = f32 ? ((const float*)a)[i] : b2f(((const bf16*)a)[i]);
    if (b)  v += f32 ? ((const float*)b)[i] : b2f(((const bf16*)b)[i]);
    dst[i] = v;
}

// ---------------------------------------------------------------------------
// Pipelined recurrent step. One launch per global step s (s = 0..SEQ):
//   blocks  0..15 : layer-1 step s     (64 hidden cols/block, K=1024)
//   blocks 16..47 : layer-2 step s-1   (32 hidden cols/block, K=2048 fused)
// Cross-launch stream ordering provides the data dependency.
// y1 is a 2-slot ring (layer-2 consumes it one launch later); y2 full history.
// MFMA 16x16x32 bf16, fp32 accumulate, h stored bf16.
// ---------------------------------------------------------------------------
__global__ __launch_bounds__(256) void rnn_step(
    int s,
    const int*  __restrict__ x,       // (S,B) int32
    const void* __restrict__ Wih1raw, // (H,V) fp32 or bf16 (gather source + detect)
    const bf16* __restrict__ Whh1,    // (H,H) ws copy
    const bf16* __restrict__ Wih2,    // (H,H) ws copy
    const bf16* __restrict__ Whh2,    // (H,H) ws copy
    const float* __restrict__ bias1,  // (H) = b_ih1+b_hh1
    const float* __restrict__ bias2,  // (H) = b_ih2+b_hh2
    bf16* y1r,                        // (2,B,H) layer-1 ring
    bf16* y2)                         // (S,B,H) layer-2 history
{
    const int bid = blockIdx.x;
    const size_t BH = (size_t)BATCH * HIDDEN;

    int layer, step, n0, NT;
    if (bid < 16) { layer = 1; step = s;     if (step >= SEQ) return; n0 = bid * 64;        NT = 4; }
    else          { layer = 2; step = s - 1; if (step < 0)    return; n0 = (bid - 16) * 32; NT = 2; }

    const int wave = threadIdx.x >> 6;
    const int lane = threadIdx.x & 63;
    const int q    = lane >> 4;      // quad 0..3
    const int l15  = lane & 15;

    const bf16 *A0, *W0, *A1, *W1;
    const float* bias;
    bf16* out;
    if (layer == 1) {
        A0 = (step == 0) ? nullptr : y1r + (size_t)((step - 1) & 1) * BH;
        W0 = Whh1; A1 = nullptr; W1 = nullptr;
        bias = bias1;
        out = y1r + (size_t)(step & 1) * BH;
    } else {
        A0 = y1r + (size_t)(step & 1) * BH;  W0 = Wih2;   // input contribution (y1[step])
        A1 = (step == 0) ? nullptr : y2 + (size_t)(step - 1) * BH;
        W1 = Whh2;                                        // recurrent contribution
        bias = bias2;
        out = y2 + (size_t)step * BH;
    }

    const int mrow = wave * 16 + l15;   // batch row this lane loads for the A frag

    f32x4 acc[4];
    #pragma unroll
    for (int t = 0; t < 4; ++t) acc[t] = (f32x4){0.f, 0.f, 0.f, 0.f};

    for (int pass = 0; pass < 2; ++pass) {
        const bf16* A = pass ? A1 : A0;
        const bf16* W = pass ? W1 : W0;
        if (A == nullptr || W == nullptr) continue;
        const bf16* arow = A + (size_t)mrow * HIDDEN + q * 8;
        for (int k0 = 0; k0 < HIDDEN; k0 += 32) {
            bf16x8 af = *(const bf16x8*)(arow + k0);
            #pragma unroll
            for (int t = 0; t < 4; ++t) {
                if (t >= NT) break;
                const bf16* wrow = W + (size_t)(n0 + t * 16 + l15) * HIDDEN + k0 + q * 8;
                bf16x8 bfr = *(const bf16x8*)wrow;
                acc[t] = __builtin_amdgcn_mfma_f32_16x16x32_bf16(af, bfr, acc[t], 0, 0, 0);
            }
        }
    }

    const bool f32in = detect_fp32(Wih1raw);

    // Epilogue: bias (+ layer-1 embedding gather) + tanh, store bf16.
    for (int t = 0; t < NT; ++t) {
        const int i = n0 + t * 16 + l15;            // hidden index (D col = lane&15)
        const float bias_i = bias[i];
        #pragma unroll
        for (int r = 0; r < 4; ++r) {
            const int b = wave * 16 + q * 4 + r;    // batch (D row = quad*4 + reg)
            float v = acc[t][r] + bias_i;
            if (layer == 1) {
                const int xv = x[step * BATCH + b];
                const size_t idx = (size_t)i * VOCAB + xv;  // one-hot(x) @ W_ih1^T gather
                v += f32in ? ((const float*)Wih1raw)[idx]
                           : b2f(((const bf16*)Wih1raw)[idx]);
            }
            v = tanhf(v);
            out[(size_t)b * HIDDEN + i] = __float2bfloat16(v);
        }
    }
}

// ---------------------------------------------------------------------------
// Final projection: ans = y2 @ W_fc^T + b_fc  -> (8192 x 5000).
// Block = 4 waves, block tile 64(M) x 128(N); wave tile 32x64.
// ---------------------------------------------------------------------------
__global__ __launch_bounds__(256) void proj(
    const bf16* __restrict__ y2,     // (S*B, H) bf16
    const bf16* __restrict__ Wfc,    // (V, H) ws bf16 copy
    const float* __restrict__ bfc,   // (V) fp32 ws copy
    void* __restrict__ outp,         // (S*B, V) fp32 or bf16
    const void* __restrict__ det)
{
    const int bn = blockIdx.x;           // 40 tiles of 128 cols
    const int bm = blockIdx.y;           // 128 tiles of 64 rows
    const int wave = threadIdx.x >> 6;
    const int lane = threadIdx.x & 63;
    const int q = lane >> 4, l15 = lane & 15;
    const int wm = wave & 1, wn = wave >> 1;
    const int m0 = bm * 64 + wm * 32;
    const int n0 = bn * 128 + wn * 64;

    f32x4 acc[2][4];
    #pragma unroll
    for (int i = 0; i < 2; ++i)
        #pragma unroll
        for (int t = 0; t < 4; ++t) acc[i][t] = (f32x4){0.f, 0.f, 0.f, 0.f};

    const bf16x8 zf = (bf16x8){0,0,0,0,0,0,0,0};
    const bf16* a0p = y2 + (size_t)(m0 + l15) * HIDDEN + q * 8;
    const bf16* a1p = a0p + (size_t)16 * HIDDEN;

    for (int k0 = 0; k0 < HIDDEN; k0 += 32) {
        bf16x8 af0 = *(const bf16x8*)(a0p + k0);
        bf16x8 af1 = *(const bf16x8*)(a1p + k0);
        #pragma unroll
        for (int t = 0; t < 4; ++t) {
            const int n = n0 + t * 16 + l15;
            bf16x8 bfr = (n < VOCAB)
                ? *(const bf16x8*)(Wfc + (size_t)n * HIDDEN + k0 + q * 8) : zf;
            acc[0][t] = __builtin_amdgcn_mfma_f32_16x16x32_bf16(af0, bfr, acc[0][t], 0, 0, 0);
            acc[1][t] = __builtin_amdgcn_mfma_f32_16x16x32_bf16(af1, bfr, acc[1][t], 0, 0, 0);
        }
    }

    const bool f32out = detect_fp32(det);

    #pragma unroll
    for (int t = 0; t < 4; ++t) {
        const int col = n0 + t * 16 + l15;
        if (col >= VOCAB) continue;
        const float bias = bfc[col];
        #pragma unroll
        for (int i = 0; i < 2; ++i)
            #pragma unroll
            for (int r = 0; r < 4; ++r) {
                const int row = m0 + i * 16 + q * 4 + r;
                const float v = acc[i][t][r] + bias;
                const size_t o = (size_t)row * VOCAB + col;
                if (f32out) ((float*)outp)[o] = v;
                else        ((bf16*)outp)[o] = __float2bfloat16(v);
            }
    }
}

// state = stack([h1_last, h2_last]) appended after ans.
__global__ __launch_bounds__(256) void state_copy(
    const bf16* __restrict__ y1r, const bf16* __restrict__ y2,
    void* __restrict__ outp, const void* __restrict__ det)
{
    const bool f32out = detect_fp32(det);
    const int t = blockIdx.x * blockDim.x + threadIdx.x;
    const int BH = BATCH * HIDDEN;
    const size_t ofs = (size_t)SEQ * BATCH * VOCAB;
    float v;
    if (t < BH)          v = b2f(y1r[(size_t)((SEQ - 1) & 1) * BH + t]);
    else                 v = b2f(y2[(size_t)(SEQ - 1) * BH + (t - BH)]);
    if (f32out) ((float*)outp)[ofs + t] = v;
    else        ((bf16*)outp)[ofs + t] = __float2bfloat16(v);
}

extern "C" void kernel_launch(void* const* d_in, const int* in_sizes, int n_in,
                              void* d_out, int out_size, void* d_ws, size_t ws_size,
                              hipStream_t stream) {
    const int*  x       = (const int*)d_in[0];
    const void* Wih1raw = d_in[1];
    const void* Whh1raw = d_in[2];
    const void* bih1    = d_in[3];
    const void* bhh1    = d_in[4];
    const void* Wih2raw = d_in[5];
    const void* Whh2raw = d_in[6];
    const void* bih2    = d_in[7];
    const void* bhh2    = d_in[8];
    const void* Wfcraw  = d_in[9];
    const void* bfcraw  = d_in[10];

    // ws layout (bf16 elems then fp32): total ~33.6 MB
    bf16*  y2    = (bf16*)d_ws;                                  // SEQ*B*H
    bf16*  y1r   = y2   + (size_t)SEQ * BATCH * HIDDEN;          // 2*B*H ring
    bf16*  whh1  = y1r  + (size_t)2 * BATCH * HIDDEN;            // H*H
    bf16*  wih2  = whh1 + (size_t)HIDDEN * HIDDEN;               // H*H
    bf16*  whh2  = wih2 + (size_t)HIDDEN * HIDDEN;               // H*H
    bf16*  wfcb  = whh2 + (size_t)HIDDEN * HIDDEN;               // V*H
    float* bias1 = (float*)(wfcb + (size_t)VOCAB * HIDDEN);      // H
    float* bias2 = bias1 + HIDDEN;                               // H
    float* bfcf  = bias2 + HIDDEN;                               // V

    const int HH = HIDDEN * HIDDEN, VH = VOCAB * HIDDEN;
    convert_w<<<(HH + 1023) / 1024, 256, 0, stream>>>(Whh1raw, whh1, HH, Wih1raw);
    convert_w<<<(HH + 1023) / 1024, 256, 0, stream>>>(Wih2raw, wih2, HH, Wih1raw);
    convert_w<<<(HH + 1023) / 1024, 256, 0, stream>>>(Whh2raw, whh2, HH, Wih1raw);
    convert_w<<<(VH + 1023) / 1024, 256, 0, stream>>>(Wfcraw,  wfcb, VH, Wih1raw);
    make_bias<<<(HIDDEN + 255) / 256, 256, 0, stream>>>(bih1, bhh1, bias1, HIDDEN, Wih1raw);
    make_bias<<<(HIDDEN + 255) / 256, 256, 0, stream>>>(bih2, bhh2, bias2, HIDDEN, Wih1raw);
    make_bias<<<(VOCAB + 255) / 256, 256, 0, stream>>>(bfcraw, nullptr, bfcf, VOCAB, Wih1raw);

    // 129 pipelined step launches: layer-1 step s and layer-2 step s-1.
    for (int s = 0; s <= SEQ; ++s)
        rnn_step<<<48, 256, 0, stream>>>(s, x, Wih1raw, whh1, wih2, whh2,
                                         bias1, bias2, y1r, y2);

    proj<<<dim3(40, 128), 256, 0, stream>>>(y2, wfcb, bfcf, d_out, Wih1raw);
    state_copy<<<(2 * BATCH * HIDDEN) / 256, 256, 0, stream>>>(y1r, y2, d_out, Wih1raw);
}

// Round 3
// 2341.987 us; speedup vs baseline: 2.0340x; 2.0340x over previous
//
#include <hip/hip_runtime.h>
#include <hip/hip_bf16.h>

#define VOCAB 5000
#define HIDDEN 1024
#define SEQ 128
#define BATCH 64
#define NBLK 96   // 32 layer-1 blocks + 64 layer-2 blocks, all co-resident

typedef __hip_bfloat16 bf16;
typedef short bf16x8 __attribute__((ext_vector_type(8)));   // 8 bf16 = 4 VGPRs (MFMA A/B frag)
typedef float f32x4 __attribute__((ext_vector_type(4)));    // MFMA C/D frag

__device__ __forceinline__ float b2f(bf16 v) { return __bfloat162float(v); }

// ---------------------------------------------------------------------------
// Dtype self-detection (see R1 note): low 16-bit halves of fp32 weights decode
// as bf16 with exp>=127 ~50% of the time; real bf16 weights (|w|<=0.03) never do.
// ---------------------------------------------------------------------------
__device__ __forceinline__ bool detect_fp32(const void* w) {
    const unsigned* p = (const unsigned*)w;
    unsigned big = 0;
    #pragma unroll
    for (int i = 0; i < 64; ++i) {
        unsigned e = (p[i] >> 7) & 0xFFu;
        big |= (e >= 127u) ? 1u : 0u;
    }
    return big != 0;
}

__global__ __launch_bounds__(256) void convert_w(const void* __restrict__ src,
                                                 bf16* __restrict__ dst, int n,
                                                 const void* __restrict__ det) {
    const bool f32 = detect_fp32(det);
    int i = (blockIdx.x * 256 + threadIdx.x) * 4;
    if (f32) {
        const float* s = (const float*)src;
        #pragma unroll
        for (int j = 0; j < 4; ++j) if (i + j < n) dst[i + j] = __float2bfloat16(s[i + j]);
    } else {
        const bf16* s = (const bf16*)src;
        #pragma unroll
        for (int j = 0; j < 4; ++j) if (i + j < n) dst[i + j] = s[i + j];
    }
}

__global__ __launch_bounds__(256) void make_bias(const void* __restrict__ a,
                                                 const void* __restrict__ b,
                                                 float* __restrict__ dst, int n,
                                                 const void* __restrict__ det) {
    const bool f32 = detect_fp32(det);
    int i = blockIdx.x * 256 + threadIdx.x;
    if (i >= n) return;
    float v = f32 ? ((const float*)a)[i] : b2f(((const bf16*)a)[i]);
    if (b)  v += f32 ? ((const float*)b)[i] : b2f(((const bf16*)b)[i]);
    dst[i] = v;
}

// ---------------------------------------------------------------------------
// Device-scope grid barrier (cross-XCD safe: release RMW + acquire spin, agent
// scope -> buffer_wbl2/buffer_inv per AMDGPU memory model). bar[] zeroed by
// hipMemsetAsync before launch; one slot per iteration.
// ---------------------------------------------------------------------------
__device__ __forceinline__ void grid_bar(int* bar, int idx) {
    __syncthreads();
    if (threadIdx.x == 0) {
        __hip_atomic_fetch_add(&bar[idx], 1, __ATOMIC_RELEASE, __HIP_MEMORY_SCOPE_AGENT);
        while (__hip_atomic_load(&bar[idx], __ATOMIC_ACQUIRE, __HIP_MEMORY_SCOPE_AGENT) < NBLK)
            __builtin_amdgcn_s_sleep(2);
    }
    __syncthreads();
}

// ---------------------------------------------------------------------------
// Persistent pipelined recurrence. One launch; s = 0..SEQ iterations:
//   blocks  0..31 : layer-1 step s    (32 hidden cols/block, K=1024)
//   blocks 32..95 : layer-2 step s-1  (16 hidden cols/block, K=2048 fused)
// Weights LDS-stationary (64 KB/block), XOR-swizzled chunks: 16B chunk c of
// row r lives at chunk index r*cpr + (c ^ (r&7))  -> ds_read_b128 at the
// 8-cycle floor. h state bounces through L2/L3 between blocks; grid barrier
// per iteration provides ordering + visibility.
// ---------------------------------------------------------------------------
__global__ __launch_bounds__(256, 1) void rnn_persistent(
    const int*  __restrict__ x,        // (S,B) int32
    const void* __restrict__ Wih1raw,  // (H,V) fp32 or bf16 (gather + detect)
    const bf16* __restrict__ whh1,     // (H,H) ws bf16
    const bf16* __restrict__ wih2,     // (H,H) ws bf16
    const bf16* __restrict__ whh2,     // (H,H) ws bf16
    const float* __restrict__ bias1,   // (H)
    const float* __restrict__ bias2,   // (H)
    bf16* __restrict__ y1r,            // (2,B,H) layer-1 ring
    bf16* __restrict__ y2,             // (S,B,H) layer-2 history
    int* __restrict__ bar)
{
    extern __shared__ bf16 lds[];      // 32768 bf16 = 64 KB
    const int bid  = blockIdx.x;
    const int tid  = threadIdx.x;
    const int wave = tid >> 6;
    const int lane = tid & 63;
    const int q    = lane >> 4;
    const int l15  = lane & 15;
    const size_t BH = (size_t)BATCH * HIDDEN;

    const bool l1  = (bid < 32);
    const int  n0  = l1 ? bid * 32 : (bid - 32) * 16;
    const int  cpr = l1 ? 128 : 256;             // 16B chunks per LDS row
    const int  rows = l1 ? 32 : 16;

    // ---- stage this block's weight slice into LDS (once) ----
    for (int idx = tid; idx < rows * cpr; idx += 256) {
        const int r = idx / 128; const int rr = l1 ? r : (r >> 1);
        const int c = idx - (idx / cpr) * cpr;
        const int row = idx / cpr;
        const bf16* src;
        if (l1) src = whh1 + (size_t)(n0 + row) * HIDDEN + c * 8;
        else {
            const bf16* W = (c < 128) ? wih2 : whh2;
            src = W + (size_t)(n0 + row) * HIDDEN + (c & 127) * 8;
        }
        (void)r; (void)rr;
        *(bf16x8*)&lds[(size_t)(row * cpr + (c ^ (row & 7))) * 8] = *(const bf16x8*)src;
    }
    __syncthreads();

    const bool f32in = detect_fp32(Wih1raw);
    const int  mrow  = wave * 16 + l15;          // batch row for A frag

    float breg[2];
    if (l1) { breg[0] = bias1[n0 + l15]; breg[1] = bias1[n0 + 16 + l15]; }
    else    { breg[0] = bias2[n0 + l15]; breg[1] = 0.f; }

    for (int s = 0; s <= SEQ; ++s) {
        if (l1) {
            if (s < SEQ) {
                const int step = s;
                // Prefetch embedding gather early (independent of GEMM).
                float xg[2][4];
                #pragma unroll
                for (int r = 0; r < 4; ++r) {
                    const int b  = wave * 16 + q * 4 + r;
                    const int xv = x[step * BATCH + b];
                    #pragma unroll
                    for (int t = 0; t < 2; ++t) {
                        const size_t gi = (size_t)(n0 + t * 16 + l15) * VOCAB + xv;
                        xg[t][r] = f32in ? ((const float*)Wih1raw)[gi]
                                         : b2f(((const bf16*)Wih1raw)[gi]);
                    }
                }
                f32x4 acc0 = {0.f,0.f,0.f,0.f}, acc1 = {0.f,0.f,0.f,0.f};
                if (step > 0) {
                    const bf16* arow = y1r + (size_t)((step - 1) & 1) * BH
                                           + (size_t)mrow * HIDDEN + q * 8;
                    for (int k0 = 0; k0 < HIDDEN; k0 += 32) {
                        bf16x8 af = *(const bf16x8*)(arow + k0);
                        const int chb = ((k0 >> 3) + q);
                        bf16x8 b0 = *(const bf16x8*)&lds[(size_t)((l15     ) * 128 + (chb ^ (l15 & 7))) * 8];
                        bf16x8 b1 = *(const bf16x8*)&lds[(size_t)((l15 + 16) * 128 + (chb ^ (l15 & 7))) * 8];
                        acc0 = __builtin_amdgcn_mfma_f32_16x16x32_bf16(af, b0, acc0, 0, 0, 0);
                        acc1 = __builtin_amdgcn_mfma_f32_16x16x32_bf16(af, b1, acc1, 0, 0, 0);
                    }
                }
                bf16* out = y1r + (size_t)(step & 1) * BH;
                #pragma unroll
                for (int t = 0; t < 2; ++t) {
                    const int i = n0 + t * 16 + l15;
                    const f32x4 a = t ? acc1 : acc0;
                    #pragma unroll
                    for (int r = 0; r < 4; ++r) {
                        const int b = wave * 16 + q * 4 + r;
                        float v = a[r] + breg[t] + xg[t][r];
                        out[(size_t)b * HIDDEN + i] = __float2bfloat16(tanhf(v));
                    }
                }
            }
        } else {
            if (s >= 1) {
                const int st = s - 1;
                f32x4 acc0 = {0.f,0.f,0.f,0.f}, acc1 = {0.f,0.f,0.f,0.f};
                // input contribution: y1[st] (slot st&1), LDS chunks 0..127
                const bf16* a1row = y1r + (size_t)(st & 1) * BH
                                        + (size_t)mrow * HIDDEN + q * 8;
                for (int k0 = 0; k0 < 1024; k0 += 64) {
                    bf16x8 afa = *(const bf16x8*)(a1row + k0);
                    bf16x8 afb = *(const bf16x8*)(a1row + k0 + 32);
                    const int ca = (((k0      ) >> 3) + q) ^ (l15 & 7);
                    const int cb = (((k0 + 32 ) >> 3) + q) ^ (l15 & 7);
                    bf16x8 ba = *(const bf16x8*)&lds[(size_t)(l15 * 256 + ca) * 8];
                    bf16x8 bb = *(const bf16x8*)&lds[(size_t)(l15 * 256 + cb) * 8];
                    acc0 = __builtin_amdgcn_mfma_f32_16x16x32_bf16(afa, ba, acc0, 0, 0, 0);
                    acc1 = __builtin_amdgcn_mfma_f32_16x16x32_bf16(afb, bb, acc1, 0, 0, 0);
                }
                // recurrent contribution: y2[st-1], LDS chunks 128..255
                if (st > 0) {
                    const bf16* a2row = y2 + (size_t)(st - 1) * BH
                                           + (size_t)mrow * HIDDEN + q * 8;
                    for (int k0 = 0; k0 < 1024; k0 += 64) {
                        bf16x8 afa = *(const bf16x8*)(a2row + k0);
                        bf16x8 afb = *(const bf16x8*)(a2row + k0 + 32);
                        const int ca = (((k0 + 1024) >> 3) + q) ^ (l15 & 7);
                        const int cb = (((k0 + 1056) >> 3) + q) ^ (l15 & 7);
                        bf16x8 ba = *(const bf16x8*)&lds[(size_t)(l15 * 256 + ca) * 8];
                        bf16x8 bb = *(const bf16x8*)&lds[(size_t)(l15 * 256 + cb) * 8];
                        acc0 = __builtin_amdgcn_mfma_f32_16x16x32_bf16(afa, ba, acc0, 0, 0, 0);
                        acc1 = __builtin_amdgcn_mfma_f32_16x16x32_bf16(afb, bb, acc1, 0, 0, 0);
                    }
                }
                bf16* out = y2 + (size_t)st * BH;
                const int i = n0 + l15;
                #pragma unroll
                for (int r = 0; r < 4; ++r) {
                    const int b = wave * 16 + q * 4 + r;
                    float v = acc0[r] + acc1[r] + breg[0];
                    out[(size_t)b * HIDDEN + i] = __float2bfloat16(tanhf(v));
                }
            }
        }
        grid_bar(bar, s);
    }
}

// ---------------------------------------------------------------------------
// Final projection: ans = y2 @ W_fc^T + b_fc  -> (8192 x 5000). Unchanged (R2).
// ---------------------------------------------------------------------------
__global__ __launch_bounds__(256) void proj(
    const bf16* __restrict__ y2, const bf16* __restrict__ Wfc,
    const float* __restrict__ bfc, void* __restrict__ outp,
    const void* __restrict__ det)
{
    const int bn = blockIdx.x;
    const int bm = blockIdx.y;
    const int wave = threadIdx.x >> 6;
    const int lane = threadIdx.x & 63;
    const int q = lane >> 4, l15 = lane & 15;
    const int wm = wave & 1, wn = wave >> 1;
    const int m0 = bm * 64 + wm * 32;
    const int n0 = bn * 128 + wn * 64;

    f32x4 acc[2][4];
    #pragma unroll
    for (int i = 0; i < 2; ++i)
        #pragma unroll
        for (int t = 0; t < 4; ++t) acc[i][t] = (f32x4){0.f, 0.f, 0.f, 0.f};

    const bf16x8 zf = (bf16x8){0,0,0,0,0,0,0,0};
    const bf16* a0p = y2 + (size_t)(m0 + l15) * HIDDEN + q * 8;
    const bf16* a1p = a0p + (size_t)16 * HIDDEN;

    for (int k0 = 0; k0 < HIDDEN; k0 += 32) {
        bf16x8 af0 = *(const bf16x8*)(a0p + k0);
        bf16x8 af1 = *(const bf16x8*)(a1p + k0);
        #pragma unroll
        for (int t = 0; t < 4; ++t) {
            const int n = n0 + t * 16 + l15;
            bf16x8 bfr = (n < VOCAB)
                ? *(const bf16x8*)(Wfc + (size_t)n * HIDDEN + k0 + q * 8) : zf;
            acc[0][t] = __builtin_amdgcn_mfma_f32_16x16x32_bf16(af0, bfr, acc[0][t], 0, 0, 0);
            acc[1][t] = __builtin_amdgcn_mfma_f32_16x16x32_bf16(af1, bfr, acc[1][t], 0, 0, 0);
        }
    }

    const bool f32out = detect_fp32(det);

    #pragma unroll
    for (int t = 0; t < 4; ++t) {
        const int col = n0 + t * 16 + l15;
        if (col >= VOCAB) continue;
        const float bias = bfc[col];
        #pragma unroll
        for (int i = 0; i < 2; ++i)
            #pragma unroll
            for (int r = 0; r < 4; ++r) {
                const int row = m0 + i * 16 + q * 4 + r;
                const float v = acc[i][t][r] + bias;
                const size_t o = (size_t)row * VOCAB + col;
                if (f32out) ((float*)outp)[o] = v;
                else        ((bf16*)outp)[o] = __float2bfloat16(v);
            }
    }
}

__global__ __launch_bounds__(256) void state_copy(
    const bf16* __restrict__ y1r, const bf16* __restrict__ y2,
    void* __restrict__ outp, const void* __restrict__ det)
{
    const bool f32out = detect_fp32(det);
    const int t = blockIdx.x * blockDim.x + threadIdx.x;
    const int BH = BATCH * HIDDEN;
    const size_t ofs = (size_t)SEQ * BATCH * VOCAB;
    float v;
    if (t < BH) v = b2f(y1r[(size_t)((SEQ - 1) & 1) * BH + t]);
    else        v = b2f(y2[(size_t)(SEQ - 1) * BH + (t - BH)]);
    if (f32out) ((float*)outp)[ofs + t] = v;
    else        ((bf16*)outp)[ofs + t] = __float2bfloat16(v);
}

extern "C" void kernel_launch(void* const* d_in, const int* in_sizes, int n_in,
                              void* d_out, int out_size, void* d_ws, size_t ws_size,
                              hipStream_t stream) {
    const int*  x       = (const int*)d_in[0];
    const void* Wih1raw = d_in[1];
    const void* Whh1raw = d_in[2];
    const void* bih1    = d_in[3];
    const void* bhh1    = d_in[4];
    const void* Wih2raw = d_in[5];
    const void* Whh2raw = d_in[6];
    const void* bih2    = d_in[7];
    const void* bhh2    = d_in[8];
    const void* Wfcraw  = d_in[9];
    const void* bfcraw  = d_in[10];

    // ws layout: barrier slots, then bf16 arrays, then fp32 biases (~33.6 MB)
    char* wsb = (char*)d_ws;
    int*   bar   = (int*)wsb;                                    // (SEQ+1) ints
    bf16*  y2    = (bf16*)(wsb + 1024);
    bf16*  y1r   = y2   + (size_t)SEQ * BATCH * HIDDEN;
    bf16*  whh1  = y1r  + (size_t)2 * BATCH * HIDDEN;
    bf16*  wih2  = whh1 + (size_t)HIDDEN * HIDDEN;
    bf16*  whh2  = wih2 + (size_t)HIDDEN * HIDDEN;
    bf16*  wfcb  = whh2 + (size_t)HIDDEN * HIDDEN;
    float* bias1 = (float*)(wfcb + (size_t)VOCAB * HIDDEN);
    float* bias2 = bias1 + HIDDEN;
    float* bfcf  = bias2 + HIDDEN;

    hipMemsetAsync(bar, 0, (SEQ + 1) * sizeof(int), stream);

    const int HH = HIDDEN * HIDDEN, VH = VOCAB * HIDDEN;
    convert_w<<<(HH + 1023) / 1024, 256, 0, stream>>>(Whh1raw, whh1, HH, Wih1raw);
    convert_w<<<(HH + 1023) / 1024, 256, 0, stream>>>(Wih2raw, wih2, HH, Wih1raw);
    convert_w<<<(HH + 1023) / 1024, 256, 0, stream>>>(Whh2raw, whh2, HH, Wih1raw);
    convert_w<<<(VH + 1023) / 1024, 256, 0, stream>>>(Wfcraw,  wfcb, VH, Wih1raw);
    make_bias<<<(HIDDEN + 255) / 256, 256, 0, stream>>>(bih1, bhh1, bias1, HIDDEN, Wih1raw);
    make_bias<<<(HIDDEN + 255) / 256, 256, 0, stream>>>(bih2, bhh2, bias2, HIDDEN, Wih1raw);
    make_bias<<<(VOCAB + 255) / 256, 256, 0, stream>>>(bfcraw, nullptr, bfcf, VOCAB, Wih1raw);

    rnn_persistent<<<NBLK, 256, 65536, stream>>>(x, Wih1raw, whh1, wih2, whh2,
                                                 bias1, bias2, y1r, y2, bar);

    proj<<<dim3(40, 128), 256, 0, stream>>>(y2, wfcb, bfcf, d_out, Wih1raw);
    state_copy<<<(2 * BATCH * HIDDEN) / 256, 256, 0, stream>>>(y1r, y2, d_out, Wih1raw);
}

// Round 4
// 2334.530 us; speedup vs baseline: 2.0405x; 1.0032x over previous
//
#include <hip/hip_runtime.h>
#include <hip/hip_bf16.h>

#define VOCAB 5000
#define HIDDEN 1024
#define SEQ 128
#define BATCH 64
#define L1NB 16   // layer-1 blocks, 64 cols each
#define L2NB 32   // layer-2 blocks, 32 cols each
#define NBLK (L1NB + L2NB)
#define RING 8    // y1 ring slots

typedef __hip_bfloat16 bf16;
typedef short bf16x8 __attribute__((ext_vector_type(8)));   // 8 bf16 = 4 VGPRs (MFMA A/B frag)
typedef float f32x4 __attribute__((ext_vector_type(4)));    // MFMA C/D frag

__device__ __forceinline__ float b2f(bf16 v) { return __bfloat162float(v); }

// ---------------------------------------------------------------------------
// Dtype self-detection (R1 note): low 16-bit halves of fp32 weights decode as
// bf16 with exp>=127 ~50% of the time; real bf16 weights (|w|<=0.03) never do.
// ---------------------------------------------------------------------------
__device__ __forceinline__ bool detect_fp32(const void* w) {
    const unsigned* p = (const unsigned*)w;
    unsigned big = 0;
    #pragma unroll
    for (int i = 0; i < 64; ++i) {
        unsigned e = (p[i] >> 7) & 0xFFu;
        big |= (e >= 127u) ? 1u : 0u;
    }
    return big != 0;
}

__global__ __launch_bounds__(256) void convert_w(const void* __restrict__ src,
                                                 bf16* __restrict__ dst, int n,
                                                 const void* __restrict__ det) {
    const bool f32 = detect_fp32(det);
    int i = (blockIdx.x * 256 + threadIdx.x) * 4;
    if (f32) {
        const float* s = (const float*)src;
        #pragma unroll
        for (int j = 0; j < 4; ++j) if (i + j < n) dst[i + j] = __float2bfloat16(s[i + j]);
    } else {
        const bf16* s = (const bf16*)src;
        #pragma unroll
        for (int j = 0; j < 4; ++j) if (i + j < n) dst[i + j] = s[i + j];
    }
}

__global__ __launch_bounds__(256) void make_bias(const void* __restrict__ a,
                                                 const void* __restrict__ b,
                                                 float* __restrict__ dst, int n,
                                                 const void* __restrict__ det) {
    const bool f32 = detect_fp32(det);
    int i = blockIdx.x * 256 + threadIdx.x;
    if (i >= n) return;
    float v = f32 ? ((const float*)a)[i] : b2f(((const bf16*)a)[i]);
    if (b)  v += f32 ? ((const float*)b)[i] : b2f(((const bf16*)b)[i]);
    dst[i] = v;
}

// ---------------------------------------------------------------------------
// Flag wait: RELAXED agent polls (no per-poll cache maintenance; agent scope
// still forces the load to the device coherence point). Every 64th poll uses
// ACQUIRE as a belt-and-braces staleness guard. Caller issues ONE acquire
// fence after all waits, then __syncthreads.
// ---------------------------------------------------------------------------
__device__ __forceinline__ void wait_flag(int* flag, int target) {
    int v = __hip_atomic_load(flag, __ATOMIC_RELAXED, __HIP_MEMORY_SCOPE_AGENT);
    int n = 0;
    while (v < target) {
        __builtin_amdgcn_s_sleep(1);
        if ((++n & 63) == 0)
            v = __hip_atomic_load(flag, __ATOMIC_ACQUIRE, __HIP_MEMORY_SCOPE_AGENT);
        else
            v = __hip_atomic_load(flag, __ATOMIC_RELAXED, __HIP_MEMORY_SCOPE_AGENT);
    }
}

// ---------------------------------------------------------------------------
// Persistent decoupled recurrence.
//   blocks  0..15 : layer-1, 64 hidden cols each, steps 0..127
//   blocks 16..47 : layer-2, 32 hidden cols each, steps 0..127 (K=2048 fused)
// Sync: f1[s] incremented by each L1 block after publishing its y1[s] slice;
// f2[t] likewise for y2[t]. L1 step s waits f1[s-1]==16 (+ f2[s-8]==32 ring
// back-pressure); L2 step t waits f1[t]==16 && f2[t-1]==32. No grid barrier.
// Weights LDS-stationary (128 KB/block), XOR-swizzled 16B chunks.
// ---------------------------------------------------------------------------
__global__ __launch_bounds__(256, 1) void rnn_persistent(
    const int*  __restrict__ x,        // (S,B) int32
    const void* __restrict__ Wih1raw,  // (H,V) fp32 or bf16 (gather + detect)
    const bf16* __restrict__ whh1,     // (H,H) ws bf16
    const bf16* __restrict__ wih2,     // (H,H) ws bf16
    const bf16* __restrict__ whh2,     // (H,H) ws bf16
    const float* __restrict__ bias1,   // (H)
    const float* __restrict__ bias2,   // (H)
    bf16* __restrict__ y1r,            // (RING,B,H) layer-1 ring
    bf16* __restrict__ y2,             // (S,B,H) layer-2 history
    int* __restrict__ f1,              // (SEQ) flags
    int* __restrict__ f2)              // (SEQ) flags
{
    extern __shared__ bf16 lds[];      // 131072 B
    const int bid  = blockIdx.x;
    const int tid  = threadIdx.x;
    const int wave = tid >> 6;
    const int lane = tid & 63;
    const int q    = lane >> 4;
    const int l15  = lane & 15;
    const size_t BH = (size_t)BATCH * HIDDEN;
    const bool f32in = detect_fp32(Wih1raw);
    const int  mrow  = wave * 16 + l15;          // batch row for A frag

    if (bid < L1NB) {
        // ================= layer 1: 64 cols =================
        const int n0 = bid * 64;
        // stage whh1 slice: 64 rows x 128 chunks (16B), swizzle c ^ (row&7)
        for (int idx = tid; idx < 64 * 128; idx += 256) {
            const int row = idx >> 7, c = idx & 127;
            *(bf16x8*)&lds[(size_t)((row << 7) + (c ^ (row & 7))) * 8] =
                *(const bf16x8*)(whh1 + (size_t)(n0 + row) * HIDDEN + c * 8);
        }
        __syncthreads();

        float breg[4];
        #pragma unroll
        for (int t = 0; t < 4; ++t) breg[t] = bias1[n0 + t * 16 + l15];

        for (int s = 0; s < SEQ; ++s) {
            // ---- embedding gather: issue before the wait (flag-independent)
            float xg[4][4];
            {
                int xv[4];
                #pragma unroll
                for (int r = 0; r < 4; ++r) xv[r] = x[s * BATCH + wave * 16 + q * 4 + r];
                #pragma unroll
                for (int t = 0; t < 4; ++t)
                    #pragma unroll
                    for (int r = 0; r < 4; ++r) {
                        const size_t gi = (size_t)(n0 + t * 16 + l15) * VOCAB + xv[r];
                        xg[t][r] = f32in ? ((const float*)Wih1raw)[gi]
                                         : b2f(((const bf16*)Wih1raw)[gi]);
                    }
            }
            if (tid == 0) {
                if (s >= 1)    wait_flag(&f1[s - 1], L1NB);
                if (s >= RING) wait_flag(&f2[s - RING], L2NB);  // ring back-pressure
                __builtin_amdgcn_fence(__ATOMIC_ACQUIRE, "agent");
            }
            __syncthreads();

            f32x4 acc[4];
            #pragma unroll
            for (int t = 0; t < 4; ++t) acc[t] = (f32x4){0.f,0.f,0.f,0.f};
            if (s > 0) {
                const bf16* arow = y1r + (size_t)((s - 1) & (RING - 1)) * BH
                                       + (size_t)mrow * HIDDEN + q * 8;
                for (int k0 = 0; k0 < HIDDEN; k0 += 32) {
                    bf16x8 af = *(const bf16x8*)(arow + k0);
                    const int chb = (k0 >> 3) + q;
                    #pragma unroll
                    for (int t = 0; t < 4; ++t) {
                        const int row = t * 16 + l15;
                        bf16x8 bw = *(const bf16x8*)&lds[(size_t)((row << 7) + (chb ^ (row & 7))) * 8];
                        acc[t] = __builtin_amdgcn_mfma_f32_16x16x32_bf16(af, bw, acc[t], 0, 0, 0);
                    }
                }
            }
            bf16* out = y1r + (size_t)(s & (RING - 1)) * BH;
            #pragma unroll
            for (int t = 0; t < 4; ++t) {
                const int i = n0 + t * 16 + l15;
                #pragma unroll
                for (int r = 0; r < 4; ++r) {
                    const int b = wave * 16 + q * 4 + r;
                    out[(size_t)b * HIDDEN + i] =
                        __float2bfloat16(tanhf(acc[t][r] + breg[t] + xg[t][r]));
                }
            }
            __syncthreads();   // drains vmcnt before the release add
            if (tid == 0)
                __hip_atomic_fetch_add(&f1[s], 1, __ATOMIC_RELEASE, __HIP_MEMORY_SCOPE_AGENT);
        }
    } else {
        // ================= layer 2: 32 cols, K=2048 =================
        const int n0 = (bid - L1NB) * 32;
        // stage [wih2|whh2] slice: 32 rows x 256 chunks
        for (int idx = tid; idx < 32 * 256; idx += 256) {
            const int row = idx >> 8, c = idx & 255;
            const bf16* W = (c < 128) ? wih2 : whh2;
            *(bf16x8*)&lds[(size_t)((row << 8) + (c ^ (row & 7))) * 8] =
                *(const bf16x8*)(W + (size_t)(n0 + row) * HIDDEN + (c & 127) * 8);
        }
        __syncthreads();

        float breg[2];
        #pragma unroll
        for (int t = 0; t < 2; ++t) breg[t] = bias2[n0 + t * 16 + l15];

        for (int st = 0; st < SEQ; ++st) {
            if (tid == 0) {
                wait_flag(&f1[st], L1NB);
                if (st >= 1) wait_flag(&f2[st - 1], L2NB);
                __builtin_amdgcn_fence(__ATOMIC_ACQUIRE, "agent");
            }
            __syncthreads();

            f32x4 acc[2];
            #pragma unroll
            for (int t = 0; t < 2; ++t) acc[t] = (f32x4){0.f,0.f,0.f,0.f};

            // pass 0: input contribution y1[st] (chunks 0..127)
            {
                const bf16* arow = y1r + (size_t)(st & (RING - 1)) * BH
                                       + (size_t)mrow * HIDDEN + q * 8;
                for (int k0 = 0; k0 < HIDDEN; k0 += 32) {
                    bf16x8 af = *(const bf16x8*)(arow + k0);
                    const int chb = (k0 >> 3) + q;
                    #pragma unroll
                    for (int t = 0; t < 2; ++t) {
                        const int row = t * 16 + l15;
                        bf16x8 bw = *(const bf16x8*)&lds[(size_t)((row << 8) + (chb ^ (row & 7))) * 8];
                        acc[t] = __builtin_amdgcn_mfma_f32_16x16x32_bf16(af, bw, acc[t], 0, 0, 0);
                    }
                }
            }
            // pass 1: recurrent contribution y2[st-1] (chunks 128..255)
            if (st > 0) {
                const bf16* arow = y2 + (size_t)(st - 1) * BH
                                      + (size_t)mrow * HIDDEN + q * 8;
                for (int k0 = 0; k0 < HIDDEN; k0 += 32) {
                    bf16x8 af = *(const bf16x8*)(arow + k0);
                    const int chb = 128 + (k0 >> 3) + q;
                    #pragma unroll
                    for (int t = 0; t < 2; ++t) {
                        const int row = t * 16 + l15;
                        bf16x8 bw = *(const bf16x8*)&lds[(size_t)((row << 8) + (chb ^ (row & 7))) * 8];
                        acc[t] = __builtin_amdgcn_mfma_f32_16x16x32_bf16(af, bw, acc[t], 0, 0, 0);
                    }
                }
            }
            bf16* out = y2 + (size_t)st * BH;
            #pragma unroll
            for (int t = 0; t < 2; ++t) {
                const int i = n0 + t * 16 + l15;
                #pragma unroll
                for (int r = 0; r < 4; ++r) {
                    const int b = wave * 16 + q * 4 + r;
                    out[(size_t)b * HIDDEN + i] =
                        __float2bfloat16(tanhf(acc[t][r] + breg[t]));
                }
            }
            __syncthreads();
            if (tid == 0)
                __hip_atomic_fetch_add(&f2[st], 1, __ATOMIC_RELEASE, __HIP_MEMORY_SCOPE_AGENT);
        }
    }
}

// ---------------------------------------------------------------------------
// Final projection: ans = y2 @ W_fc^T + b_fc -> (8192 x 5000).
// Block 64M x 256N (wave tile 32x128, 16 MFMA/k-step for ILP). Grid x=bm so
// the 512 KB B-slice stays L2-resident across the 128 row-blocks. C staged in
// LDS for full-line coalesced stores (fixes 2.3x WRITE_SIZE inflation).
// ---------------------------------------------------------------------------
__global__ __launch_bounds__(256) void proj(
    const bf16* __restrict__ y2, const bf16* __restrict__ Wfc,
    const float* __restrict__ bfc, void* __restrict__ outp,
    const void* __restrict__ det)
{
    __shared__ bf16 cbuf[64 * 256];      // 32 KB C staging
    const int bm = blockIdx.x;           // 128 row tiles
    const int bn = blockIdx.y;           // 20 col tiles of 256
    const int wave = threadIdx.x >> 6;
    const int lane = threadIdx.x & 63;
    const int q = lane >> 4, l15 = lane & 15;
    const int wm = wave & 1, wn = wave >> 1;
    const int m0 = bm * 64 + wm * 32;
    const int n0 = bn * 256 + wn * 128;

    f32x4 acc[2][8];
    #pragma unroll
    for (int i = 0; i < 2; ++i)
        #pragma unroll
        for (int t = 0; t < 8; ++t) acc[i][t] = (f32x4){0.f,0.f,0.f,0.f};

    const bf16x8 zf = (bf16x8){0,0,0,0,0,0,0,0};
    const bf16* a0p = y2 + (size_t)(m0 + l15) * HIDDEN + q * 8;
    const bf16* a1p = a0p + (size_t)16 * HIDDEN;

    for (int k0 = 0; k0 < HIDDEN; k0 += 32) {
        bf16x8 af0 = *(const bf16x8*)(a0p + k0);
        bf16x8 af1 = *(const bf16x8*)(a1p + k0);
        #pragma unroll
        for (int t = 0; t < 8; ++t) {
            const int n = n0 + t * 16 + l15;
            bf16x8 bw = (n < VOCAB)
                ? *(const bf16x8*)(Wfc + (size_t)n * HIDDEN + k0 + q * 8) : zf;
            acc[0][t] = __builtin_amdgcn_mfma_f32_16x16x32_bf16(af0, bw, acc[0][t], 0, 0, 0);
            acc[1][t] = __builtin_amdgcn_mfma_f32_16x16x32_bf16(af1, bw, acc[1][t], 0, 0, 0);
        }
    }

    const bool f32out = detect_fp32(det);

    if (f32out) {
        #pragma unroll
        for (int t = 0; t < 8; ++t) {
            const int col = n0 + t * 16 + l15;
            if (col >= VOCAB) continue;
            const float bias = bfc[col];
            #pragma unroll
            for (int i = 0; i < 2; ++i)
                #pragma unroll
                for (int r = 0; r < 4; ++r) {
                    const int row = m0 + i * 16 + q * 4 + r;
                    ((float*)outp)[(size_t)row * VOCAB + col] = acc[i][t][r] + bias;
                }
        }
        return;
    }

    // bf16 path: stage in LDS, store coalesced 16B/lane full lines.
    #pragma unroll
    for (int t = 0; t < 8; ++t) {
        const int col  = n0 + t * 16 + l15;
        const int cloc = wn * 128 + t * 16 + l15;
        const float bias = (col < VOCAB) ? bfc[col] : 0.f;
        #pragma unroll
        for (int i = 0; i < 2; ++i)
            #pragma unroll
            for (int r = 0; r < 4; ++r) {
                const int rloc = wm * 32 + i * 16 + q * 4 + r;
                cbuf[rloc * 256 + cloc] = __float2bfloat16(acc[i][t][r] + bias);
            }
    }
    __syncthreads();
    bf16* ob = (bf16*)outp;
    for (int cidx = threadIdx.x; cidx < 64 * 32; cidx += 256) {
        const int row = cidx >> 5;
        const int c8  = (cidx & 31) * 8;
        const int gcol = bn * 256 + c8;          // VOCAB % 8 == 0: chunk all-in/out
        if (gcol < VOCAB)
            *(bf16x8*)(ob + (size_t)(bm * 64 + row) * VOCAB + gcol) =
                *(const bf16x8*)&cbuf[row * 256 + c8];
    }
}

__global__ __launch_bounds__(256) void state_copy(
    const bf16* __restrict__ y1r, const bf16* __restrict__ y2,
    void* __restrict__ outp, const void* __restrict__ det)
{
    const bool f32out = detect_fp32(det);
    const int t = blockIdx.x * blockDim.x + threadIdx.x;
    const int BH = BATCH * HIDDEN;
    const size_t ofs = (size_t)SEQ * BATCH * VOCAB;
    float v;
    if (t < BH) v = b2f(y1r[(size_t)((SEQ - 1) & (RING - 1)) * BH + t]);
    else        v = b2f(y2[(size_t)(SEQ - 1) * BH + (t - BH)]);
    if (f32out) ((float*)outp)[ofs + t] = v;
    else        ((bf16*)outp)[ofs + t] = __float2bfloat16(v);
}

extern "C" void kernel_launch(void* const* d_in, const int* in_sizes, int n_in,
                              void* d_out, int out_size, void* d_ws, size_t ws_size,
                              hipStream_t stream) {
    const int*  x       = (const int*)d_in[0];
    const void* Wih1raw = d_in[1];
    const void* Whh1raw = d_in[2];
    const void* bih1    = d_in[3];
    const void* bhh1    = d_in[4];
    const void* Wih2raw = d_in[5];
    const void* Whh2raw = d_in[6];
    const void* bih2    = d_in[7];
    const void* bhh2    = d_in[8];
    const void* Wfcraw  = d_in[9];
    const void* bfcraw  = d_in[10];

    // ws layout: flags (1 KB), bf16 arrays, fp32 biases (~34.2 MB total)
    char* wsb = (char*)d_ws;
    int*   f1    = (int*)wsb;                                    // SEQ ints
    int*   f2    = f1 + SEQ;                                     // SEQ ints
    bf16*  y2    = (bf16*)(wsb + 1024);
    bf16*  y1r   = y2   + (size_t)SEQ * BATCH * HIDDEN;          // RING*B*H
    bf16*  whh1  = y1r  + (size_t)RING * BATCH * HIDDEN;
    bf16*  wih2  = whh1 + (size_t)HIDDEN * HIDDEN;
    bf16*  whh2  = wih2 + (size_t)HIDDEN * HIDDEN;
    bf16*  wfcb  = whh2 + (size_t)HIDDEN * HIDDEN;
    float* bias1 = (float*)(wfcb + (size_t)VOCAB * HIDDEN);
    float* bias2 = bias1 + HIDDEN;
    float* bfcf  = bias2 + HIDDEN;

    hipMemsetAsync(f1, 0, 2 * SEQ * sizeof(int), stream);

    const int HH = HIDDEN * HIDDEN, VH = VOCAB * HIDDEN;
    convert_w<<<(HH + 1023) / 1024, 256, 0, stream>>>(Whh1raw, whh1, HH, Wih1raw);
    convert_w<<<(HH + 1023) / 1024, 256, 0, stream>>>(Wih2raw, wih2, HH, Wih1raw);
    convert_w<<<(HH + 1023) / 1024, 256, 0, stream>>>(Whh2raw, whh2, HH, Wih1raw);
    convert_w<<<(VH + 1023) / 1024, 256, 0, stream>>>(Wfcraw,  wfcb, VH, Wih1raw);
    make_bias<<<(HIDDEN + 255) / 256, 256, 0, stream>>>(bih1, bhh1, bias1, HIDDEN, Wih1raw);
    make_bias<<<(HIDDEN + 255) / 256, 256, 0, stream>>>(bih2, bhh2, bias2, HIDDEN, Wih1raw);
    make_bias<<<(VOCAB + 255) / 256, 256, 0, stream>>>(bfcraw, nullptr, bfcf, VOCAB, Wih1raw);

    rnn_persistent<<<NBLK, 256, 131072, stream>>>(x, Wih1raw, whh1, wih2, whh2,
                                                  bias1, bias2, y1r, y2, f1, f2);

    proj<<<dim3(128, 20), 256, 0, stream>>>(y2, wfcb, bfcf, d_out, Wih1raw);
    state_copy<<<(2 * BATCH * HIDDEN) / 256, 256, 0, stream>>>(y1r, y2, d_out, Wih1raw);
}